// Round 3
// baseline (607.814 us; speedup 1.0000x reference)
//
#include <hip/hip_runtime.h>
#include <hip/hip_bf16.h>

// Fused Conv3d(3->16,k=3,valid) + conv_b + ReLU + maxpool2x2x2
// + spatial mean(fp32) + /2 + bias + channel-sum  ->  out[32] fp32.
//
// Inputs arrive as FLOAT32 (harness materializes the reference's fp16 as f32;
// evidence: u16/bf16 interpretation gave deterministic inf from low mantissa
// halves). We convert x, conv_w to bf16 (RNE) in-kernel for the MFMA.
//
// Implicit GEMM via mfma_f32_16x16x32_bf16:
//   A = weights [M=16 ch][K=27 taps (ci,kd,kh) pad 32], registers.
//   B = im2col  [K][N=16 w-positions], LDS, kw dim = 3 MFMAs w/ shifted B cols.
//   D layout (m89-verified): col = lane&15 = w-position, row = q*4+r = channel.
// One block = (b, dp, hp): 4 conv rows (2d x 2h) x 128 w x 16 ch; full 2x2x2
// pool closes in-register (dh running max, w-pair via shfl_xor 1).

typedef __attribute__((ext_vector_type(8))) short short8;
typedef __attribute__((ext_vector_type(4))) float floatx4;

__device__ __forceinline__ short f2bf(float f) {
    // fp32 -> bf16 bits, round-to-nearest-even (inputs are finite)
    unsigned u = __builtin_bit_cast(unsigned, f);
    unsigned r = (u + 0x7FFFu + ((u >> 16) & 1u)) >> 16;
    return (short)r;
}

#define TAPS_PAD 40   // shorts per im2col column (80 B: 16B-aligned, bank-clean)
#define NCOL 130      // cols 0..127 staged, 128..129 explicitly zeroed

__global__ __launch_bounds__(512) void fused_conv_pool_reduce(
    const float* __restrict__ xg,    // f32 [32][3][32][128][128]
    const float* __restrict__ wg,    // f32 [16][3][3][3][3]
    const float* __restrict__ cbg,   // f32 [16]
    float* __restrict__ out)         // f32 [32]
{
    __shared__ __align__(16) short xs[4][NCOL][TAPS_PAD];  // 41,600 B
    __shared__ float wsums[8];

    const int hp  = blockIdx.x;   // 0..62
    const int dp  = blockIdx.y;   // 0..14
    const int b   = blockIdx.z;   // 0..31
    const int tid = threadIdx.x;  // 0..511
    const int lane = tid & 63;
    const int wv   = tid >> 6;    // wave id = w-tile 0..7

    const int m = lane & 15;      // A-operand row (output channel)
    const int q = lane >> 4;      // K-quad

    // ---- A fragments (weights): A[m][k=q*8+j], one per kw ----
    // tap t = ci*9 + kd*3 + kh ; conv_w index = m*81 + t*3 + kw
    short8 afrag[3];
    #pragma unroll
    for (int kw = 0; kw < 3; ++kw) {
        #pragma unroll
        for (int j = 0; j < 8; ++j) {
            const int k = q * 8 + j;
            afrag[kw][j] = (k < 27) ? f2bf(wg[m * 81 + k * 3 + kw]) : (short)0;
        }
    }

    // ---- zero pad columns 128..129 (read by wave 7's kw-shifted B loads) ----
    if (tid < 320) {
        const int dhz = tid / 80;
        const int rem = tid % 80;
        xs[dhz][128 + rem / 40][rem % 40] = 0;
    }

    // ---- stage im2col columns: thread = (dh, w) column, 27 f32 loads ----
    {
        const int dhi = tid >> 7;        // 0..3 : dd = dhi>>1, hh = dhi&1
        const int w   = tid & 127;
        const int dd = dhi >> 1, hh = dhi & 1;
        const int zb = 2 * dp + dd;      // conv d base; reads zb..zb+2 <= 31
        const int yb = 2 * hp + hh;      // conv h base; reads yb..yb+2 <= 127
        float vals[27];
        #pragma unroll
        for (int ci = 0; ci < 3; ++ci) {
            #pragma unroll
            for (int kd = 0; kd < 3; ++kd) {
                #pragma unroll
                for (int kh = 0; kh < 3; ++kh) {
                    vals[ci * 9 + kd * 3 + kh] =
                        xg[(((size_t)(b * 3 + ci) * 32 + (zb + kd)) * 128 + (yb + kh)) * 128 + w];
                }
            }
        }
        short* col = &xs[dhi][w][0];
        #pragma unroll
        for (int blk = 0; blk < 4; ++blk) {          // 4x ds_write_b128 per column
            short8 pk;
            #pragma unroll
            for (int j = 0; j < 8; ++j) {
                const int t = blk * 8 + j;
                pk[j] = (t < 27) ? f2bf(vals[t]) : (short)0;  // zero-pad K 27..31
            }
            *(short8*)(col + blk * 8) = pk;
        }
    }
    __syncthreads();

    // ---- compute: wave = one 16-wide w-tile, 4 (dd,hh) rows, pool in-reg ----
    const int n  = lane & 15;     // w position within tile (N = D col)
    const int w0 = wv * 16;
    floatx4 mx = {-3.0e38f, -3.0e38f, -3.0e38f, -3.0e38f};
    #pragma unroll
    for (int dh = 0; dh < 4; ++dh) {
        floatx4 acc = {0.f, 0.f, 0.f, 0.f};
        #pragma unroll
        for (int kw = 0; kw < 3; ++kw) {
            const short8 bfr = *(const short8*)(&xs[dh][w0 + n + kw][q * 8]);
            acc = __builtin_amdgcn_mfma_f32_16x16x32_bf16(afrag[kw], bfr, acc, 0, 0, 0);
        }
        #pragma unroll
        for (int r = 0; r < 4; ++r) mx[r] = fmaxf(mx[r], acc[r]);  // pool over d,h
    }

    // D row (channel) = q*4 + r. relu(max + conv_b[ch]); bias-after-max valid
    // (same bias for all 8 pooled candidates; relu commutes with max).
    float vsum = 0.f;
    #pragma unroll
    for (int r = 0; r < 4; ++r) {
        const float cb = cbg[q * 4 + r];
        float v = fmaxf(mx[r] + cb, 0.f);
        float o = __shfl_xor(v, 1, 64);              // pool over w pair (n, n^1)
        vsum += fmaxf(v, o);
    }
    // valid pooled column: even n, pair base w0+(n&14) <= 124  (conv W = 126)
    const bool ok = ((lane & 1) == 0) && (w0 + (n & 14) <= 124);
    float s = ok ? vsum : 0.f;
    #pragma unroll
    for (int off = 1; off < 64; off <<= 1) s += __shfl_xor(s, off, 64);

    if (lane == 0) wsums[wv] = s;
    __syncthreads();
    if (tid == 0) {
        float bs = 0.f;
        #pragma unroll
        for (int i = 0; i < 8; ++i) bs += wsums[i];
        // out[b] += sum_pooled / (15*63*63) / 2
        atomicAdd(&out[b], bs * (1.0f / 119070.0f));
    }
}

__global__ void init_out_kernel(const float* __restrict__ biasg,
                                float* __restrict__ out) {
    const int b = threadIdx.x;
    if (b < 32) {
        float s = 0.f;
        #pragma unroll
        for (int cc = 0; cc < 16; ++cc) s += biasg[cc];
        out[b] = s;   // out[b] starts at sum_c bias_c; conv blocks atomicAdd the rest
    }
}

extern "C" void kernel_launch(void* const* d_in, const int* in_sizes, int n_in,
                              void* d_out, int out_size, void* d_ws, size_t ws_size,
                              hipStream_t stream) {
    const float* x      = (const float*)d_in[0];
    const float* conv_w = (const float*)d_in[1];
    const float* conv_b = (const float*)d_in[2];
    const float* bias   = (const float*)d_in[3];
    float* out = (float*)d_out;

    init_out_kernel<<<1, 32, 0, stream>>>(bias, out);
    dim3 grid(63, 15, 32);  // (hp, dp, b)
    fused_conv_pool_reduce<<<grid, 512, 0, stream>>>(x, conv_w, conv_b, out);
}